// Round 1
// baseline (31.359 us; speedup 1.0000x reference)
//
#include <hip/hip_runtime.h>

#define EPS_ROT   1e-6f
#define EPS_FRAME 1e-8f

// ---------- small matrix helpers (all fully unrolled, registers only) ----------

__device__ __forceinline__ void loadMat4(const float* __restrict__ p, float B[4][4]) {
    const float4* q = reinterpret_cast<const float4*>(p);
#pragma unroll
    for (int i = 0; i < 4; ++i) {
        float4 r = q[i];
        B[i][0] = r.x; B[i][1] = r.y; B[i][2] = r.z; B[i][3] = r.w;
    }
}

__device__ __forceinline__ void storeMat4(float* __restrict__ p, const float M[4][4]) {
    float4* q = reinterpret_cast<float4*>(p);
#pragma unroll
    for (int i = 0; i < 4; ++i)
        q[i] = make_float4(M[i][0], M[i][1], M[i][2], M[i][3]);
}

// C = A * B, A is affine given as 3 rows of 4 (row3 implicitly [0,0,0,1])
__device__ __forceinline__ void affineMul(const float a[3][4], const float B[4][4], float C[4][4]) {
#pragma unroll
    for (int i = 0; i < 3; ++i)
#pragma unroll
        for (int j = 0; j < 4; ++j)
            C[i][j] = a[i][0]*B[0][j] + a[i][1]*B[1][j] + a[i][2]*B[2][j] + a[i][3]*B[3][j];
#pragma unroll
    for (int j = 0; j < 4; ++j) C[3][j] = B[3][j];
}

// C = A * B, both full 4x4
__device__ __forceinline__ void mat4Mul(const float A[4][4], const float B[4][4], float C[4][4]) {
#pragma unroll
    for (int i = 0; i < 4; ++i)
#pragma unroll
        for (int j = 0; j < 4; ++j)
            C[i][j] = A[i][0]*B[0][j] + A[i][1]*B[1][j] + A[i][2]*B[2][j] + A[i][3]*B[3][j];
}

// M = M @ rotX(c,s): only columns 1,2 change
__device__ __forceinline__ void postRotX(float M[4][4], float c, float s) {
#pragma unroll
    for (int i = 0; i < 4; ++i) {
        float m1 = M[i][1], m2 = M[i][2];
        M[i][1] = c*m1 + s*m2;
        M[i][2] = c*m2 - s*m1;
    }
}

// M = M @ rotZ(c,s): only columns 0,1 change
__device__ __forceinline__ void postRotZ(float M[4][4], float c, float s) {
#pragma unroll
    for (int i = 0; i < 4; ++i) {
        float m0 = M[i][0], m1 = M[i][1];
        M[i][0] = c*m0 + s*m1;
        M[i][1] = c*m1 - s*m0;
    }
}

// 3x3 axis-angle rotation (u assumed unit)
__device__ __forceinline__ void rotAxis3(float G[3][3], float c, float s,
                                         float u0, float u1, float u2) {
    float omc = 1.0f - c;
    G[0][0] = c + u0*u0*omc;    G[0][1] = u0*u1*omc - u2*s; G[0][2] = u0*u2*omc + u1*s;
    G[1][0] = u0*u1*omc + u2*s; G[1][1] = c + u1*u1*omc;    G[1][2] = u1*u2*omc - u0*s;
    G[2][0] = u0*u2*omc - u1*s; G[2][1] = u1*u2*omc + u0*s; G[2][2] = c + u2*u2*omc;
}

__device__ __forceinline__ void mat3Mul(const float A[3][3], const float B[3][3], float C[3][3]) {
#pragma unroll
    for (int i = 0; i < 3; ++i)
#pragma unroll
        for (int j = 0; j < 3; ++j)
            C[i][j] = A[i][0]*B[0][j] + A[i][1]*B[1][j] + A[i][2]*B[2][j];
}

// ---------------------------- kernel A: 9 frames per residue ----------------------------

__global__ __launch_bounds__(256) void frames_kernel(
    const int*   __restrict__ seq,     // (BL)
    const float* __restrict__ xyz,     // (BL,3,3)
    const float* __restrict__ alphas,  // (BL,10,2)
    const float* __restrict__ RTs,     // (NAA,7,4,4)
    const float* __restrict__ xibf,    // (NAA,36,4)
    float*       __restrict__ out,     // (BL,9,4,4)
    int BL)
{
    int t = blockIdx.x * 256 + threadIdx.x;
    if (t >= BL) return;
    int s = seq[t];

    // ---- rigid_from_3_points on backbone N, Ca, C ----
    const float* p = xyz + (size_t)t * 9;
    float N0=p[0], N1=p[1], N2=p[2];
    float A0=p[3], A1=p[4], A2=p[5];
    float C0=p[6], C1=p[7], C2=p[8];

    float v10=C0-A0, v11=C1-A1, v12=C2-A2;   // C - Ca
    float v20=N0-A0, v21=N1-A1, v22=N2-A2;   // N - Ca
    float n1 = sqrtf(v10*v10 + v11*v11 + v12*v12) + EPS_FRAME;
    float e10=v10/n1, e11=v11/n1, e12=v12/n1;
    float d  = e10*v20 + e11*v21 + e12*v22;
    float u20=v20-e10*d, u21=v21-e11*d, u22=v22-e12*d;
    float n2 = sqrtf(u20*u20 + u21*u21 + u22*u22) + EPS_FRAME;
    float e20=u20/n2, e21=u21/n2, e22=u22/n2;
    float e30=e11*e22 - e12*e21;
    float e31=e12*e20 - e10*e22;
    float e32=e10*e21 - e11*e20;

    // RTF0 affine: rows (with translation in col 3). R columns are e1,e2,e3.
    float f0[3][4] = { {e10, e20, e30, A0},
                       {e11, e21, e31, A1},
                       {e12, e22, e32, A2} };

    // ---- alphas: 10 normalized (cos,sin) pairs ----
    float ca[10], sa[10];
    {
        const float4* a4 = reinterpret_cast<const float4*>(alphas + (size_t)t * 20);
#pragma unroll
        for (int k = 0; k < 5; ++k) {
            float4 v = a4[k];
            float na = sqrtf(v.x*v.x + v.y*v.y) + EPS_ROT;
            ca[2*k]   = v.x/na; sa[2*k]   = v.y/na;
            float nb = sqrtf(v.z*v.z + v.w*v.w) + EPS_ROT;
            ca[2*k+1] = v.z/nb; sa[2*k+1] = v.w/nb;
        }
    }

    float* fo = out + (size_t)t * 144;
    const float* rb = RTs + (size_t)s * 112;

    // frame 0
    {
        float F0[4][4] = { {f0[0][0], f0[0][1], f0[0][2], f0[0][3]},
                           {f0[1][0], f0[1][1], f0[1][2], f0[1][3]},
                           {f0[2][0], f0[2][1], f0[2][2], f0[2][3]},
                           {0.f, 0.f, 0.f, 1.f} };
        storeMat4(fo, F0);
    }

    // frames 1..3:  RTF0 @ RT_base[i] @ rotX(alpha_i)
    float Bm[4][4], T[4][4];
#pragma unroll
    for (int i = 0; i < 3; ++i) {
        loadMat4(rb + i*16, Bm);
        affineMul(f0, Bm, T);
        postRotX(T, ca[i], sa[i]);
        storeMat4(fo + (i+1)*16, T);
    }

    // ---- CB rotation axes from base geometry ----
    const float* bxp = xibf + (size_t)s * 144;
    float4 b0 = reinterpret_cast<const float4*>(bxp)[0];   // atom 0
    float4 b1 = reinterpret_cast<const float4*>(bxp)[1];   // atom 1 (CA)
    float4 b2 = reinterpret_cast<const float4*>(bxp)[2];   // atom 2
    float4 b4 = reinterpret_cast<const float4*>(bxp)[4];   // atom 4 (CB)

    float NCr0 = 0.5f*(b2.x + b0.x), NCr1 = 0.5f*(b2.y + b0.y), NCr2 = 0.5f*(b2.z + b0.z);
    float ba0 = b4.x - b1.x, ba1 = b4.y - b1.y, ba2 = b4.z - b1.z;          // CB - CA
    float w0 = NCr0 - b1.x, w1 = NCr1 - b1.y, w2 = NCr2 - b1.z;             // NCr - CA
    // ax1 = normalize(cross(ba, w))
    float x10 = ba1*w2 - ba2*w1, x11 = ba2*w0 - ba0*w2, x12 = ba0*w1 - ba1*w0;
    float xn1 = sqrtf(x10*x10 + x11*x11 + x12*x12) + 1e-8f;
    x10 /= xn1; x11 /= xn1; x12 /= xn1;
    // NCpp
    float NCp0 = b2.x - b0.x, NCp1 = b2.y - b0.y, NCp2 = b2.z - b0.z;
    float dp = NCp0*NCr0 + NCp1*NCr1 + NCp2*NCr2;
    float dr = NCr0*NCr0 + NCr1*NCr1 + NCr2*NCr2;
    float sfac = dp / dr;
    float q0 = NCp0 - sfac*NCr0, q1 = NCp1 - sfac*NCr1, q2 = NCp2 - sfac*NCr2;
    // ax2 = normalize(cross(ba, q))
    float x20 = ba1*q2 - ba2*q1, x21 = ba2*q0 - ba0*q2, x22 = ba0*q1 - ba1*q0;
    float xn2 = sqrtf(x20*x20 + x21*x21 + x22*x22) + 1e-8f;
    x20 /= xn2; x21 /= xn2; x22 /= xn2;

    // RTF8 = RTF0 @ rotAxis(a7,ax1) @ rotAxis(a8,ax2) : affine, T unchanged
    float G1[3][3], G2[3][3], G12[3][3], R8[3][3];
    rotAxis3(G1, ca[7], sa[7], x10, x11, x12);
    rotAxis3(G2, ca[8], sa[8], x20, x21, x22);
    mat3Mul(G1, G2, G12);
    {
        float R0[3][3] = { {f0[0][0], f0[0][1], f0[0][2]},
                           {f0[1][0], f0[1][1], f0[1][2]},
                           {f0[2][0], f0[2][1], f0[2][2]} };
        mat3Mul(R0, G12, R8);
    }
    float f8[3][4] = { {R8[0][0], R8[0][1], R8[0][2], f0[0][3]},
                       {R8[1][0], R8[1][1], R8[1][2], f0[1][3]},
                       {R8[2][0], R8[2][1], R8[2][2], f0[2][3]} };
    {
        float F8[4][4] = { {f8[0][0], f8[0][1], f8[0][2], f8[0][3]},
                           {f8[1][0], f8[1][1], f8[1][2], f8[1][3]},
                           {f8[2][0], f8[2][1], f8[2][2], f8[2][3]},
                           {0.f, 0.f, 0.f, 1.f} };
        storeMat4(fo + 8*16, F8);
    }

    // RTF4 = RTF8 @ RT_base[3] @ rotX(a3) @ rotZ(a9)
    float F4[4][4];
    loadMat4(rb + 3*16, Bm);
    affineMul(f8, Bm, F4);
    postRotX(F4, ca[3], sa[3]);
    postRotZ(F4, ca[9], sa[9]);
    storeMat4(fo + 4*16, F4);

    // RTF5..7 chain
    float F5[4][4], F6[4][4], F7[4][4];
    loadMat4(rb + 4*16, Bm);
    mat4Mul(F4, Bm, F5);
    postRotX(F5, ca[4], sa[4]);
    storeMat4(fo + 5*16, F5);

    loadMat4(rb + 5*16, Bm);
    mat4Mul(F5, Bm, F6);
    postRotX(F6, ca[5], sa[5]);
    storeMat4(fo + 6*16, F6);

    loadMat4(rb + 6*16, Bm);
    mat4Mul(F6, Bm, F7);
    postRotX(F7, ca[6], sa[6]);
    storeMat4(fo + 7*16, F7);
}

// ---------------------------- kernel B: atom transforms ----------------------------

__global__ __launch_bounds__(256) void atoms_kernel(
    const int*   __restrict__ seq,      // (BL)
    const int*   __restrict__ bidx,     // (NAA,36)
    const float* __restrict__ xibf,     // (NAA,36,4)
    const float* __restrict__ frames,   // (BL,9,4,4) — written by frames_kernel
    float*       __restrict__ out_xyz,  // (BL,36,3)
    int BL)
{
    int g = blockIdx.x * 256 + threadIdx.x;
    if (g >= BL * 36) return;
    int t = g / 36;
    int a = g - t * 36;
    int s = seq[t];
    int idx = bidx[s * 36 + a];

    const float4* fr = reinterpret_cast<const float4*>(frames + ((size_t)t * 9 + idx) * 16);
    float4 r0 = fr[0], r1 = fr[1], r2 = fr[2];
    float4 v  = reinterpret_cast<const float4*>(xibf + ((size_t)s * 36 + a) * 4)[0];

    float x = r0.x*v.x + r0.y*v.y + r0.z*v.z + r0.w*v.w;
    float y = r1.x*v.x + r1.y*v.y + r1.z*v.z + r1.w*v.w;
    float z = r2.x*v.x + r2.y*v.y + r2.z*v.z + r2.w*v.w;

    size_t o = (size_t)g * 3;
    out_xyz[o+0] = x;
    out_xyz[o+1] = y;
    out_xyz[o+2] = z;
}

// ---------------------------- launch ----------------------------

extern "C" void kernel_launch(void* const* d_in, const int* in_sizes, int n_in,
                              void* d_out, int out_size, void* d_ws, size_t ws_size,
                              hipStream_t stream) {
    const int*   seq    = (const int*)  d_in[0];
    const float* xyz    = (const float*)d_in[1];
    const float* alphas = (const float*)d_in[2];
    const int*   bidx   = (const int*)  d_in[3];
    const float* RTs    = (const float*)d_in[4];
    const float* xibf   = (const float*)d_in[5];
    float*       out    = (float*)d_out;

    int BL = in_sizes[0];                 // B * L
    float* out_xyz = out + (size_t)BL * 144;

    frames_kernel<<<(BL + 255) / 256, 256, 0, stream>>>(seq, xyz, alphas, RTs, xibf, out, BL);
    atoms_kernel<<<(BL * 36 + 255) / 256, 256, 0, stream>>>(seq, bidx, xibf, out, out_xyz, BL);
}

// Round 2
// 16.543 us; speedup vs baseline: 1.8956x; 1.8956x over previous
//
#include <hip/hip_runtime.h>

#define EPS_ROT   1e-6f
#define EPS_FRAME 1e-8f

#define RPB 64              // residues per block
#define FRS 20              // frame stride in LDS floats (16 + 4 pad -> spreads banks)
#define RSS (9*FRS)         // residue stride in LDS floats
#define PSTR 36             // P-exchange stride (2 mats + 4 pad)

// ---------- helpers ----------

__device__ __forceinline__ void angNorm(float x, float y, float& c, float& s) {
    float n = sqrtf(x*x + y*y) + EPS_ROT;
    c = x / n; s = y / n;
}

__device__ __forceinline__ void loadMat4(const float* __restrict__ p, float B[4][4]) {
    const float4* q = reinterpret_cast<const float4*>(p);
#pragma unroll
    for (int i = 0; i < 4; ++i) {
        float4 r = q[i];
        B[i][0] = r.x; B[i][1] = r.y; B[i][2] = r.z; B[i][3] = r.w;
    }
}

__device__ __forceinline__ void storeMatLDS(float* dst, const float M[4][4]) {
#pragma unroll
    for (int i = 0; i < 4; ++i)
        *reinterpret_cast<float4*>(dst + i*4) = make_float4(M[i][0], M[i][1], M[i][2], M[i][3]);
}

// C = A * B, A affine as 3 rows of 4 (row3 implicitly [0,0,0,1]); C row3 = B row3
__device__ __forceinline__ void affineMul(const float a[3][4], const float B[4][4], float C[4][4]) {
#pragma unroll
    for (int i = 0; i < 3; ++i)
#pragma unroll
        for (int j = 0; j < 4; ++j)
            C[i][j] = a[i][0]*B[0][j] + a[i][1]*B[1][j] + a[i][2]*B[2][j] + a[i][3]*B[3][j];
#pragma unroll
    for (int j = 0; j < 4; ++j) C[3][j] = B[3][j];
}

__device__ __forceinline__ void mat4Mul(const float A[4][4], const float B[4][4], float C[4][4]) {
#pragma unroll
    for (int i = 0; i < 4; ++i)
#pragma unroll
        for (int j = 0; j < 4; ++j)
            C[i][j] = A[i][0]*B[0][j] + A[i][1]*B[1][j] + A[i][2]*B[2][j] + A[i][3]*B[3][j];
}

// M = M @ rotX(c,s): only columns 1,2 change
__device__ __forceinline__ void postRotX(float M[4][4], float c, float s) {
#pragma unroll
    for (int i = 0; i < 4; ++i) {
        float m1 = M[i][1], m2 = M[i][2];
        M[i][1] = c*m1 + s*m2;
        M[i][2] = c*m2 - s*m1;
    }
}

__device__ __forceinline__ void rotAxis3(float G[3][3], float c, float s,
                                         float u0, float u1, float u2) {
    float omc = 1.0f - c;
    G[0][0] = c + u0*u0*omc;    G[0][1] = u0*u1*omc - u2*s; G[0][2] = u0*u2*omc + u1*s;
    G[1][0] = u0*u1*omc + u2*s; G[1][1] = c + u1*u1*omc;    G[1][2] = u1*u2*omc - u0*s;
    G[2][0] = u0*u2*omc - u1*s; G[2][1] = u1*u2*omc + u0*s; G[2][2] = c + u2*u2*omc;
}

__device__ __forceinline__ void mat3Mul(const float A[3][3], const float B[3][3], float C[3][3]) {
#pragma unroll
    for (int i = 0; i < 3; ++i)
#pragma unroll
        for (int j = 0; j < 3; ++j)
            C[i][j] = A[i][0]*B[0][j] + A[i][1]*B[1][j] + A[i][2]*B[2][j];
}

// rigid_from_3_points -> affine rows {R | T}, R columns are e1,e2,e3
__device__ __forceinline__ void computeF0(const float* __restrict__ xyz, int t, float f0[3][4]) {
    const float* p = xyz + (size_t)t * 9;
    float N0=p[0], N1=p[1], N2=p[2];
    float A0=p[3], A1=p[4], A2=p[5];
    float C0=p[6], C1=p[7], C2=p[8];

    float v10=C0-A0, v11=C1-A1, v12=C2-A2;
    float v20=N0-A0, v21=N1-A1, v22=N2-A2;
    float n1 = sqrtf(v10*v10 + v11*v11 + v12*v12) + EPS_FRAME;
    float e10=v10/n1, e11=v11/n1, e12=v12/n1;
    float d  = e10*v20 + e11*v21 + e12*v22;
    float u20=v20-e10*d, u21=v21-e11*d, u22=v22-e12*d;
    float n2 = sqrtf(u20*u20 + u21*u21 + u22*u22) + EPS_FRAME;
    float e20=u20/n2, e21=u21/n2, e22=u22/n2;
    float e30=e11*e22 - e12*e21;
    float e31=e12*e20 - e10*e22;
    float e32=e10*e21 - e11*e20;

    f0[0][0]=e10; f0[0][1]=e20; f0[0][2]=e30; f0[0][3]=A0;
    f0[1][0]=e11; f0[1][1]=e21; f0[1][2]=e31; f0[1][3]=A1;
    f0[2][0]=e12; f0[2][1]=e22; f0[2][2]=e32; f0[2][3]=A2;
}

// ---------------------------- fused kernel ----------------------------
// block = 256 threads = 4 waves, 64 residues. Waves specialize:
//  wv0: F0, F1          wv1: F2, F3
//  wv2: axes, F8        wv3: P4..P7 chain (base-frame only)
// barrier; wv2: F4=F8*P4, F5=F8*P5; wv3: F6=F8*P6, F7=F8*P7 (F8 via LDS)
// barrier; all: coalesced frames LDS->global + atom transforms from LDS.

__global__ __launch_bounds__(256) void fused_kernel(
    const int*   __restrict__ seq,     // (BL)
    const float* __restrict__ xyz,     // (BL,3,3)
    const float* __restrict__ alphas,  // (BL,10,2)
    const int*   __restrict__ bidx,    // (NAA,36)
    const float* __restrict__ RTs,     // (NAA,7,4,4)
    const float* __restrict__ xibf,    // (NAA,36,4)
    float*       __restrict__ out_fr,  // (BL,9,4,4)
    float*       __restrict__ out_xyz, // (BL,36,3)
    int BL)
{
    __shared__ float lds_fr[RPB * RSS];
    __shared__ float lds_P[RPB * PSTR];
    __shared__ int   lds_seq[RPB];

    const int tid = threadIdx.x;
    const int wv  = tid >> 6;
    const int r   = tid & 63;
    const int base = blockIdx.x * RPB;
    const int t   = base + r;
    const bool valid = (t < BL);

    int s = 0;
    if (valid) s = seq[t];
    const float* rb = RTs + (size_t)s * 112;
    const float* al = alphas + (size_t)t * 20;
    float* fl = lds_fr + r * RSS;

    // registers carried across barrier 1
    float f8[3][4];                 // wave 2
    float P6[4][4], P7[4][4];       // wave 3

    if (valid) {
        if (wv == 0) {
            lds_seq[r] = s;
            float f0[3][4]; computeF0(xyz, t, f0);
            float F0[4][4] = { {f0[0][0],f0[0][1],f0[0][2],f0[0][3]},
                               {f0[1][0],f0[1][1],f0[1][2],f0[1][3]},
                               {f0[2][0],f0[2][1],f0[2][2],f0[2][3]},
                               {0.f,0.f,0.f,1.f} };
            storeMatLDS(fl + 0*FRS, F0);

            float2 a0 = *reinterpret_cast<const float2*>(al + 0);
            float c0, s0; angNorm(a0.x, a0.y, c0, s0);
            float B[4][4]; loadMat4(rb + 0, B);
            float F[4][4]; affineMul(f0, B, F); postRotX(F, c0, s0);
            storeMatLDS(fl + 1*FRS, F);
        } else if (wv == 1) {
            float f0[3][4]; computeF0(xyz, t, f0);
            float2 a1 = *reinterpret_cast<const float2*>(al + 2);
            float2 a2 = *reinterpret_cast<const float2*>(al + 4);
            float c, sn;
            float B[4][4], F[4][4];
            angNorm(a1.x, a1.y, c, sn);
            loadMat4(rb + 16, B); affineMul(f0, B, F); postRotX(F, c, sn);
            storeMatLDS(fl + 2*FRS, F);
            angNorm(a2.x, a2.y, c, sn);
            loadMat4(rb + 32, B); affineMul(f0, B, F); postRotX(F, c, sn);
            storeMatLDS(fl + 3*FRS, F);
        } else if (wv == 2) {
            float f0[3][4]; computeF0(xyz, t, f0);
            // CB rotation axes from base geometry
            const float* bxp = xibf + (size_t)s * 144;
            float4 b0 = reinterpret_cast<const float4*>(bxp)[0];
            float4 b1 = reinterpret_cast<const float4*>(bxp)[1];
            float4 b2 = reinterpret_cast<const float4*>(bxp)[2];
            float4 b4 = reinterpret_cast<const float4*>(bxp)[4];

            float NCr0 = 0.5f*(b2.x + b0.x), NCr1 = 0.5f*(b2.y + b0.y), NCr2 = 0.5f*(b2.z + b0.z);
            float ba0 = b4.x - b1.x, ba1 = b4.y - b1.y, ba2 = b4.z - b1.z;
            float w0 = NCr0 - b1.x, w1 = NCr1 - b1.y, w2 = NCr2 - b1.z;
            float x10 = ba1*w2 - ba2*w1, x11 = ba2*w0 - ba0*w2, x12 = ba0*w1 - ba1*w0;
            float xn1 = sqrtf(x10*x10 + x11*x11 + x12*x12) + 1e-8f;
            x10 /= xn1; x11 /= xn1; x12 /= xn1;
            float NCp0 = b2.x - b0.x, NCp1 = b2.y - b0.y, NCp2 = b2.z - b0.z;
            float dp = NCp0*NCr0 + NCp1*NCr1 + NCp2*NCr2;
            float dr = NCr0*NCr0 + NCr1*NCr1 + NCr2*NCr2;
            float sf = dp / dr;
            float q0 = NCp0 - sf*NCr0, q1 = NCp1 - sf*NCr1, q2 = NCp2 - sf*NCr2;
            float x20 = ba1*q2 - ba2*q1, x21 = ba2*q0 - ba0*q2, x22 = ba0*q1 - ba1*q0;
            float xn2 = sqrtf(x20*x20 + x21*x21 + x22*x22) + 1e-8f;
            x20 /= xn2; x21 /= xn2; x22 /= xn2;

            float2 a7 = *reinterpret_cast<const float2*>(al + 14);
            float2 a8 = *reinterpret_cast<const float2*>(al + 16);
            float c7, s7, c8, s8;
            angNorm(a7.x, a7.y, c7, s7);
            angNorm(a8.x, a8.y, c8, s8);
            float G1[3][3], G2[3][3], G12[3][3], R8[3][3];
            rotAxis3(G1, c7, s7, x10, x11, x12);
            rotAxis3(G2, c8, s8, x20, x21, x22);
            mat3Mul(G1, G2, G12);
            float R0[3][3] = { {f0[0][0],f0[0][1],f0[0][2]},
                               {f0[1][0],f0[1][1],f0[1][2]},
                               {f0[2][0],f0[2][1],f0[2][2]} };
            mat3Mul(R0, G12, R8);
#pragma unroll
            for (int i = 0; i < 3; ++i) {
                f8[i][0] = R8[i][0]; f8[i][1] = R8[i][1]; f8[i][2] = R8[i][2];
                f8[i][3] = f0[i][3];
            }
            float F8[4][4] = { {f8[0][0],f8[0][1],f8[0][2],f8[0][3]},
                               {f8[1][0],f8[1][1],f8[1][2],f8[1][3]},
                               {f8[2][0],f8[2][1],f8[2][2],f8[2][3]},
                               {0.f,0.f,0.f,1.f} };
            storeMatLDS(fl + 8*FRS, F8);
        } else {
            // wv == 3: suffix chain in base coordinates
            float2 a3 = *reinterpret_cast<const float2*>(al + 6);
            float2 a4 = *reinterpret_cast<const float2*>(al + 8);
            float2 a5 = *reinterpret_cast<const float2*>(al + 10);
            float2 a6 = *reinterpret_cast<const float2*>(al + 12);
            float2 a9 = *reinterpret_cast<const float2*>(al + 18);
            float c3,s3, c4,s4, c5,s5, c6,s6, c9,s9;
            angNorm(a3.x, a3.y, c3, s3);
            angNorm(a4.x, a4.y, c4, s4);
            angNorm(a5.x, a5.y, c5, s5);
            angNorm(a6.x, a6.y, c6, s6);
            angNorm(a9.x, a9.y, c9, s9);

            // M = rotX(c3,s3) @ rotZ(c9,s9), 3x3 (col3 = e3 implicitly)
            float M00 = c9,     M01 = -s9;               // M02 = 0
            float M10 = c3*s9,  M11 = c3*c9,  M12 = -s3;
            float M20 = s3*s9,  M21 = s3*c9,  M22 = c3;

            float B[4][4]; loadMat4(rb + 48, B);
            float P4[4][4];
#pragma unroll
            for (int i = 0; i < 4; ++i) {
                P4[i][0] = B[i][0]*M00 + B[i][1]*M10 + B[i][2]*M20;
                P4[i][1] = B[i][0]*M01 + B[i][1]*M11 + B[i][2]*M21;
                P4[i][2] =               B[i][1]*M12 + B[i][2]*M22;
                P4[i][3] = B[i][3];
            }
            float P5[4][4];
            loadMat4(rb + 64, B); mat4Mul(P4, B, P5); postRotX(P5, c4, s4);
            loadMat4(rb + 80, B); mat4Mul(P5, B, P6); postRotX(P6, c5, s5);
            loadMat4(rb + 96, B); mat4Mul(P6, B, P7); postRotX(P7, c6, s6);

            float* pl = lds_P + r * PSTR;
            storeMatLDS(pl,      P4);
            storeMatLDS(pl + 16, P5);
        }
    }
    __syncthreads();

    if (valid) {
        if (wv == 2) {
            const float* pl = lds_P + r * PSTR;
            float P[4][4], F[4][4];
            loadMat4(pl, P);
            affineMul(f8, P, F); storeMatLDS(fl + 4*FRS, F);
            loadMat4(pl + 16, P);
            affineMul(f8, P, F); storeMatLDS(fl + 5*FRS, F);
        } else if (wv == 3) {
            float f8b[3][4];
            const float* q = fl + 8*FRS;
#pragma unroll
            for (int i = 0; i < 3; ++i) {
                float4 v = *reinterpret_cast<const float4*>(q + i*4);
                f8b[i][0] = v.x; f8b[i][1] = v.y; f8b[i][2] = v.z; f8b[i][3] = v.w;
            }
            float F[4][4];
            affineMul(f8b, P6, F); storeMatLDS(fl + 6*FRS, F);
            affineMul(f8b, P7, F); storeMatLDS(fl + 7*FRS, F);
        }
    }
    __syncthreads();

    // phase 2a: frames LDS -> global, fully coalesced float4 stores
    for (int c = tid; c < RPB*36; c += 256) {
        int res = c / 36;
        int q = c - res*36;
        int tt = base + res;
        if (tt < BL) {
            float4 v = *reinterpret_cast<const float4*>(
                lds_fr + res*RSS + (q >> 2)*FRS + (q & 3)*4);
            *reinterpret_cast<float4*>(out_fr + (size_t)tt*144 + q*4) = v;
        }
    }

    // phase 2b: atom transforms, frames read from LDS
    for (int c = tid; c < RPB*36; c += 256) {
        int res = c / 36;
        int a = c - res*36;
        int tt = base + res;
        if (tt < BL) {
            int ss = lds_seq[res];
            int idx = bidx[ss*36 + a];
            const float* fp = lds_fr + res*RSS + idx*FRS;
            float4 r0 = *reinterpret_cast<const float4*>(fp);
            float4 r1 = *reinterpret_cast<const float4*>(fp + 4);
            float4 r2 = *reinterpret_cast<const float4*>(fp + 8);
            float4 v  = *reinterpret_cast<const float4*>(xibf + ((size_t)ss*36 + a)*4);
            size_t o = (size_t)tt*108 + (size_t)a*3;
            out_xyz[o+0] = r0.x*v.x + r0.y*v.y + r0.z*v.z + r0.w*v.w;
            out_xyz[o+1] = r1.x*v.x + r1.y*v.y + r1.z*v.z + r1.w*v.w;
            out_xyz[o+2] = r2.x*v.x + r2.y*v.y + r2.z*v.z + r2.w*v.w;
        }
    }
}

// ---------------------------- launch ----------------------------

extern "C" void kernel_launch(void* const* d_in, const int* in_sizes, int n_in,
                              void* d_out, int out_size, void* d_ws, size_t ws_size,
                              hipStream_t stream) {
    const int*   seq    = (const int*)  d_in[0];
    const float* xyz    = (const float*)d_in[1];
    const float* alphas = (const float*)d_in[2];
    const int*   bidx   = (const int*)  d_in[3];
    const float* RTs    = (const float*)d_in[4];
    const float* xibf   = (const float*)d_in[5];
    float*       out    = (float*)d_out;

    int BL = in_sizes[0];                       // B * L
    float* out_xyz = out + (size_t)BL * 144;

    int blocks = (BL + RPB - 1) / RPB;
    fused_kernel<<<blocks, 256, 0, stream>>>(seq, xyz, alphas, bidx, RTs, xibf,
                                             out, out_xyz, BL);
}